// Round 1
// baseline (417.792 us; speedup 1.0000x reference)
//
#include <hip/hip_runtime.h>

#define D 256

// ---------------- CSR build ----------------

__global__ void k_hist(const int* __restrict__ dst, int E, int* __restrict__ deg) {
    int e = blockIdx.x * blockDim.x + threadIdx.x;
    if (e < E) atomicAdd(&deg[dst[e]], 1);
}

// per-1024-block inclusive scan of deg -> rs[i+1]; block totals -> bsums
__global__ void k_scan_block(const int* __restrict__ deg, int N,
                             int* __restrict__ rs, int* __restrict__ bsums) {
    __shared__ int s[1024];
    int base = blockIdx.x * 1024;
    int t = threadIdx.x;
    int v = (base + t < N) ? deg[base + t] : 0;
    s[t] = v;
    __syncthreads();
    for (int off = 1; off < 1024; off <<= 1) {
        int add = (t >= off) ? s[t - off] : 0;
        __syncthreads();
        s[t] += add;
        __syncthreads();
    }
    if (base + t < N) rs[base + t + 1] = s[t];
    if (t == 1023) bsums[blockIdx.x] = s[1023];
}

// exclusive scan of block sums (nb <= 1024)
__global__ void k_scan_sums(int* __restrict__ bsums, int nb) {
    __shared__ int s[1024];
    int t = threadIdx.x;
    int v = (t < nb) ? bsums[t] : 0;
    s[t] = v;
    __syncthreads();
    for (int off = 1; off < 1024; off <<= 1) {
        int add = (t >= off) ? s[t - off] : 0;
        __syncthreads();
        s[t] += add;
        __syncthreads();
    }
    if (t < nb) bsums[t] = s[t] - v;
}

__global__ void k_finalize_rs(int N, int* __restrict__ rs, const int* __restrict__ bsums) {
    int i = blockIdx.x * blockDim.x + threadIdx.x;
    if (i < N) rs[i + 1] += bsums[i >> 10];
    if (i == 0) rs[0] = 0;
}

__global__ void k_fill(const int* __restrict__ src, const int* __restrict__ dst, int E,
                       const int* __restrict__ rs, int* __restrict__ cursor,
                       int* __restrict__ csr) {
    int e = blockIdx.x * blockDim.x + threadIdx.x;
    if (e < E) {
        int d = dst[e];
        int p = atomicAdd(&cursor[d], 1);
        csr[rs[d] + p] = src[e];
    }
}

// ---------------- message mean + combine: x = tgt + mean(src over csr) ----------------
// one wave (64 lanes) per target row; lane handles 4 consecutive floats

__global__ void k_msg_x(const float* __restrict__ srcf, const float* __restrict__ tgtf,
                        const int* __restrict__ rs, const int* __restrict__ csr,
                        int N, float* __restrict__ xout) {
    int wave = (blockIdx.x * blockDim.x + threadIdx.x) >> 6;
    int lane = threadIdx.x & 63;
    if (wave >= N) return;
    int s0 = rs[wave], s1 = rs[wave + 1];
    float4 acc = make_float4(0.f, 0.f, 0.f, 0.f);
    for (int i = s0; i < s1; i++) {
        int s = csr[i];
        float4 f = *(const float4*)&srcf[(size_t)s * D + lane * 4];
        acc.x += f.x; acc.y += f.y; acc.z += f.z; acc.w += f.w;
    }
    int cnt = s1 - s0;
    float inv = 1.0f / (float)(cnt > 0 ? cnt : 1);
    float4 t = *(const float4*)&tgtf[(size_t)wave * D + lane * 4];
    float4 x;
    x.x = t.x + acc.x * inv;
    x.y = t.y + acc.y * inv;
    x.z = t.z + acc.z * inv;
    x.w = t.w + acc.w * inv;
    *(float4*)&xout[(size_t)wave * D + lane * 4] = x;
}

// ---------------- GEMM (fp32) + bias + ReLU + LayerNorm, in-place capable ----------------
// block: 256 threads = 4 waves; 32 rows x 256 cols output tile.
// wave wg owns rows wg*8..wg*8+7; lane owns cols lane*4..lane*4+3.

__launch_bounds__(256)
__global__ void k_gemm_ln(const float* __restrict__ X, const float* __restrict__ W,
                          const float* __restrict__ bias, const float* __restrict__ gamma,
                          const float* __restrict__ beta, int N, float* __restrict__ Y) {
    __shared__ float As[32][36];   // padded: row stride 144B (16B-aligned)
    __shared__ float Bs[32][256];  // 32 KB

    int t = threadIdx.x;
    int lane = t & 63;
    int wg = t >> 6;
    int row0 = blockIdx.x * 32;

    float acc[8][4] = {};

    for (int k0 = 0; k0 < D; k0 += 32) {
        // A tile: 32 rows x 32 k
        {
            int i = t >> 3;
            int j = (t & 7) * 4;
            int r = row0 + i;
            float4 a = make_float4(0.f, 0.f, 0.f, 0.f);
            if (r < N) a = *(const float4*)&X[(size_t)r * D + k0 + j];
            *(float4*)&As[i][j] = a;
        }
        // B tile: 32 k x 256 cols
        #pragma unroll
        for (int rep = 0; rep < 8; rep++) {
            int f = rep * 256 + t;        // float4 index in [0, 2048)
            int r = f >> 6;               // 0..31
            int c = (f & 63) * 4;         // 0..252
            *(float4*)&Bs[r][c] = *(const float4*)&W[(size_t)(k0 + r) * D + c];
        }
        __syncthreads();

        #pragma unroll
        for (int kk = 0; kk < 32; kk++) {
            float4 b = *(float4*)&Bs[kk][lane * 4];
            #pragma unroll
            for (int r = 0; r < 8; r++) {
                float a = As[wg * 8 + r][kk];
                acc[r][0] += a * b.x;
                acc[r][1] += a * b.y;
                acc[r][2] += a * b.z;
                acc[r][3] += a * b.w;
            }
        }
        __syncthreads();
    }

    // epilogue: bias + relu + layernorm per row (wave-level reduce)
    float4 bv = *(const float4*)&bias[lane * 4];
    float4 gv = *(const float4*)&gamma[lane * 4];
    float4 bev = *(const float4*)&beta[lane * 4];

    #pragma unroll
    for (int r = 0; r < 8; r++) {
        int row = row0 + wg * 8 + r;
        if (row >= N) continue;
        float v0 = fmaxf(acc[r][0] + bv.x, 0.f);
        float v1 = fmaxf(acc[r][1] + bv.y, 0.f);
        float v2 = fmaxf(acc[r][2] + bv.z, 0.f);
        float v3 = fmaxf(acc[r][3] + bv.w, 0.f);
        float sum = v0 + v1 + v2 + v3;
        float sq  = v0 * v0 + v1 * v1 + v2 * v2 + v3 * v3;
        #pragma unroll
        for (int off = 1; off < 64; off <<= 1) {
            sum += __shfl_xor(sum, off);
            sq  += __shfl_xor(sq, off);
        }
        float mu  = sum * (1.0f / 256.0f);
        float var = sq * (1.0f / 256.0f) - mu * mu;
        float rstd = rsqrtf(var + 1e-5f);
        float4 o;
        o.x = (v0 - mu) * rstd * gv.x + bev.x;
        o.y = (v1 - mu) * rstd * gv.y + bev.y;
        o.z = (v2 - mu) * rstd * gv.z + bev.z;
        o.w = (v3 - mu) * rstd * gv.w + bev.w;
        *(float4*)&Y[(size_t)row * D + lane * 4] = o;
    }
}

// ---------------- launch ----------------

extern "C" void kernel_launch(void* const* d_in, const int* in_sizes, int n_in,
                              void* d_out, int out_size, void* d_ws, size_t ws_size,
                              hipStream_t stream) {
    const float* uf    = (const float*)d_in[0];
    const float* itf   = (const float*)d_in[1];
    const int*   ui_e  = (const int*)d_in[2];   // [2, Eui] user->item
    const int*   iu_e  = (const int*)d_in[3];   // [2, Eiu] item->user
    const float* Wu    = (const float*)d_in[4];
    const float* bu    = (const float*)d_in[5];
    const float* Wi    = (const float*)d_in[6];
    const float* bi    = (const float*)d_in[7];
    const float* gamma = (const float*)d_in[8];
    const float* beta  = (const float*)d_in[9];

    int NU  = in_sizes[0] / D;
    int NI  = in_sizes[1] / D;
    int Eui = in_sizes[2] / 2;
    int Eiu = in_sizes[3] / 2;
    int Nmax = NU > NI ? NU : NI;

    float* out   = (float*)d_out;
    float* u_out = out;
    float* i_out = out + (size_t)NU * D;

    // ws layout (ints)
    int* deg    = (int*)d_ws;
    int* rs     = deg + Nmax;          // Nmax+1
    int* bsums  = rs + Nmax + 1;       // 1024
    int* cursor = bsums + 1024;        // Nmax
    int* csr    = cursor + Nmax;       // Emax

    auto run_side = [&](const float* srcf, const float* tgtf, const int* edges, int E,
                        int N, const float* W, const float* bias, float* y) {
        const int* esrc = edges;
        const int* edst = edges + E;
        hipMemsetAsync(deg, 0, (size_t)N * sizeof(int), stream);
        hipMemsetAsync(cursor, 0, (size_t)N * sizeof(int), stream);
        k_hist<<<(E + 255) / 256, 256, 0, stream>>>(edst, E, deg);
        int nb = (N + 1023) / 1024;
        k_scan_block<<<nb, 1024, 0, stream>>>(deg, N, rs, bsums);
        k_scan_sums<<<1, 1024, 0, stream>>>(bsums, nb);
        k_finalize_rs<<<(N + 255) / 256, 256, 0, stream>>>(N, rs, bsums);
        k_fill<<<(E + 255) / 256, 256, 0, stream>>>(esrc, edst, E, rs, cursor, csr);
        k_msg_x<<<(N + 3) / 4, 256, 0, stream>>>(srcf, tgtf, rs, csr, N, y);
        k_gemm_ln<<<(N + 31) / 32, 256, 0, stream>>>(y, W, bias, gamma, beta, N, y);
    };

    // users: messages from items via item_user_edge_index
    run_side(itf, uf, iu_e, Eiu, NU, Wu, bu, u_out);
    // items: messages from users via user_item_edge_index
    run_side(uf, itf, ui_e, Eui, NI, Wi, bi, i_out);
}

// Round 2
// 290.440 us; speedup vs baseline: 1.4385x; 1.4385x over previous
//
#include <hip/hip_runtime.h>
#include <hip/hip_bf16.h>

#define D 256
#define BM 64
#define BK 64
#define LDK 72   // padded LDS k-stride (144B rows: 16B-aligned, 2-way bank alias = free)

typedef __attribute__((ext_vector_type(8))) __bf16 bf16x8;
typedef __attribute__((ext_vector_type(4))) float f32x4;

// ---------------- CSR build ----------------

__global__ void k_hist(const int* __restrict__ dst, int E, int* __restrict__ deg) {
    int e = blockIdx.x * blockDim.x + threadIdx.x;
    if (e < E) atomicAdd(&deg[dst[e]], 1);
}

__global__ void k_scan_block(const int* __restrict__ deg, int N,
                             int* __restrict__ rs, int* __restrict__ bsums) {
    __shared__ int s[1024];
    int base = blockIdx.x * 1024;
    int t = threadIdx.x;
    int v = (base + t < N) ? deg[base + t] : 0;
    s[t] = v;
    __syncthreads();
    for (int off = 1; off < 1024; off <<= 1) {
        int add = (t >= off) ? s[t - off] : 0;
        __syncthreads();
        s[t] += add;
        __syncthreads();
    }
    if (base + t < N) rs[base + t + 1] = s[t];
    if (t == 1023) bsums[blockIdx.x] = s[1023];
}

__global__ void k_scan_sums(int* __restrict__ bsums, int nb) {
    __shared__ int s[1024];
    int t = threadIdx.x;
    int v = (t < nb) ? bsums[t] : 0;
    s[t] = v;
    __syncthreads();
    for (int off = 1; off < 1024; off <<= 1) {
        int add = (t >= off) ? s[t - off] : 0;
        __syncthreads();
        s[t] += add;
        __syncthreads();
    }
    if (t < nb) bsums[t] = s[t] - v;
}

__global__ void k_finalize_rs(int N, int* __restrict__ rs, const int* __restrict__ bsums) {
    int i = blockIdx.x * blockDim.x + threadIdx.x;
    if (i < N) rs[i + 1] += bsums[i >> 10];
    if (i == 0) rs[0] = 0;
}

__global__ void k_fill(const int* __restrict__ src, const int* __restrict__ dst, int E,
                       const int* __restrict__ rs, int* __restrict__ cursor,
                       int* __restrict__ csr) {
    int e = blockIdx.x * blockDim.x + threadIdx.x;
    if (e < E) {
        int d = dst[e];
        int p = atomicAdd(&cursor[d], 1);
        csr[rs[d] + p] = src[e];
    }
}

// ---------------- message mean + combine: x = tgt + mean(src over csr) ----------------

__global__ void k_msg_x(const float* __restrict__ srcf, const float* __restrict__ tgtf,
                        const int* __restrict__ rs, const int* __restrict__ csr,
                        int N, float* __restrict__ xout) {
    int wave = (blockIdx.x * blockDim.x + threadIdx.x) >> 6;
    int lane = threadIdx.x & 63;
    if (wave >= N) return;
    int s0 = rs[wave], s1 = rs[wave + 1];
    float4 acc = make_float4(0.f, 0.f, 0.f, 0.f);
    for (int i = s0; i < s1; i++) {
        int s = csr[i];
        float4 f = *(const float4*)&srcf[(size_t)s * D + lane * 4];
        acc.x += f.x; acc.y += f.y; acc.z += f.z; acc.w += f.w;
    }
    int cnt = s1 - s0;
    float inv = 1.0f / (float)(cnt > 0 ? cnt : 1);
    float4 t = *(const float4*)&tgtf[(size_t)wave * D + lane * 4];
    float4 x;
    x.x = t.x + acc.x * inv;
    x.y = t.y + acc.y * inv;
    x.z = t.z + acc.z * inv;
    x.w = t.w + acc.w * inv;
    *(float4*)&xout[(size_t)wave * D + lane * 4] = x;
}

// ---------------- W transpose + convert: Wt[c][k] = bf16(W[k][c]) ----------------
// 512 blocks x 256 threads: block < 256 -> Wu row k, else Wi row k.

__global__ void k_wcvt(const float* __restrict__ W0, const float* __restrict__ W1,
                       __hip_bfloat16* __restrict__ Wt0, __hip_bfloat16* __restrict__ Wt1) {
    int b = blockIdx.x;
    const float* W = (b < 256) ? W0 : W1;
    __hip_bfloat16* Wt = (b < 256) ? Wt0 : Wt1;
    int k = b & 255;
    int c = threadIdx.x;
    Wt[(size_t)c * 256 + k] = __float2bfloat16(W[(size_t)k * 256 + c]);
}

// ---------------- bf16-MFMA GEMM + bias + ReLU + LayerNorm (in-place on X==Y) ----------
// block: 256 threads = 4 waves. Tile: 64 rows x 256 cols, BK=64.
// wave w owns cols [w*64, w*64+64); per wave 4x4 grid of 16x16 frags.

__launch_bounds__(256)
__global__ void k_gemm_mfma_ln(const float* __restrict__ X,
                               const __hip_bfloat16* __restrict__ Wt,
                               const float* __restrict__ bias,
                               const float* __restrict__ gamma,
                               const float* __restrict__ beta,
                               int N, float* __restrict__ Y) {
    __shared__ __hip_bfloat16 As[BM][LDK];   // 9216 B
    __shared__ __hip_bfloat16 Bs[D][LDK];    // 36864 B
    __shared__ float red_s[BM][4];
    __shared__ float red_q[BM][4];

    int t = threadIdx.x;
    int lane = t & 63;
    int w = t >> 6;
    int l15 = lane & 15;
    int l4 = lane >> 4;
    int row0 = blockIdx.x * BM;

    f32x4 acc[4][4];
    f32x4 zero = {0.f, 0.f, 0.f, 0.f};
    #pragma unroll
    for (int fr = 0; fr < 4; fr++)
        #pragma unroll
        for (int fc = 0; fc < 4; fc++)
            acc[fr][fc] = zero;

    for (int k0 = 0; k0 < D; k0 += BK) {
        // ---- stage A: 64 rows x 64 k, fp32 -> bf16. thread t: row i=t>>2, k-quad (t&3)*16
        {
            int i = t >> 2;
            int kq = (t & 3) * 16;
            int r = row0 + i;
            float4 f[4];
            if (r < N) {
                const float4* p = (const float4*)&X[(size_t)r * D + k0 + kq];
                f[0] = p[0]; f[1] = p[1]; f[2] = p[2]; f[3] = p[3];
            } else {
                float4 z4 = make_float4(0.f, 0.f, 0.f, 0.f);
                f[0] = z4; f[1] = z4; f[2] = z4; f[3] = z4;
            }
            __hip_bfloat16 vb[16];
            #pragma unroll
            for (int q = 0; q < 4; q++) {
                vb[q * 4 + 0] = __float2bfloat16(f[q].x);
                vb[q * 4 + 1] = __float2bfloat16(f[q].y);
                vb[q * 4 + 2] = __float2bfloat16(f[q].z);
                vb[q * 4 + 3] = __float2bfloat16(f[q].w);
            }
            *(uint4*)&As[i][kq]     = *(uint4*)&vb[0];
            *(uint4*)&As[i][kq + 8] = *(uint4*)&vb[8];
        }
        // ---- stage B: 256 cols x 64 k from Wt (already [c][k] bf16)
        #pragma unroll
        for (int pass = 0; pass < 4; pass++) {
            int c = pass * 64 + (t >> 2);
            int kq = (t & 3) * 16;
            const uint4* p = (const uint4*)&Wt[(size_t)c * D + k0 + kq];
            uint4 b0 = p[0], b1 = p[1];
            *(uint4*)&Bs[c][kq]     = b0;
            *(uint4*)&Bs[c][kq + 8] = b1;
        }
        __syncthreads();

        // ---- MFMA: 2 k-steps of 32
        #pragma unroll
        for (int ks = 0; ks < 2; ks++) {
            bf16x8 af[4], bg[4];
            #pragma unroll
            for (int fr = 0; fr < 4; fr++)
                af[fr] = *(const bf16x8*)&As[fr * 16 + l15][ks * 32 + l4 * 8];
            #pragma unroll
            for (int fc = 0; fc < 4; fc++)
                bg[fc] = *(const bf16x8*)&Bs[w * 64 + fc * 16 + l15][ks * 32 + l4 * 8];
            #pragma unroll
            for (int fr = 0; fr < 4; fr++)
                #pragma unroll
                for (int fc = 0; fc < 4; fc++)
                    acc[fr][fc] = __builtin_amdgcn_mfma_f32_16x16x32_bf16(
                        af[fr], bg[fc], acc[fr][fc], 0, 0, 0);
        }
        __syncthreads();
    }

    // ---- epilogue: bias + relu, per-row partial sums (this wave's 64 cols)
    float bias_c[4], gam_c[4], bet_c[4];
    #pragma unroll
    for (int fc = 0; fc < 4; fc++) {
        int col = w * 64 + fc * 16 + l15;
        bias_c[fc] = bias[col];
        gam_c[fc]  = gamma[col];
        bet_c[fc]  = beta[col];
    }

    #pragma unroll
    for (int fr = 0; fr < 4; fr++) {
        #pragma unroll
        for (int r = 0; r < 4; r++) {
            int row = fr * 16 + l4 * 4 + r;
            float s = 0.f, q = 0.f;
            #pragma unroll
            for (int fc = 0; fc < 4; fc++) {
                float v = acc[fr][fc][r] + bias_c[fc];
                v = fmaxf(v, 0.f);
                acc[fr][fc][r] = v;
                s += v;
                q += v * v;
            }
            #pragma unroll
            for (int m = 1; m < 16; m <<= 1) {
                s += __shfl_xor(s, m);
                q += __shfl_xor(q, m);
            }
            if (l15 == 0) { red_s[row][w] = s; red_q[row][w] = q; }
        }
    }
    __syncthreads();

    // ---- cross-wave LN + store
    #pragma unroll
    for (int fr = 0; fr < 4; fr++) {
        #pragma unroll
        for (int r = 0; r < 4; r++) {
            int row = fr * 16 + l4 * 4 + r;
            int grow = row0 + row;
            if (grow >= N) continue;
            float s = red_s[row][0] + red_s[row][1] + red_s[row][2] + red_s[row][3];
            float q = red_q[row][0] + red_q[row][1] + red_q[row][2] + red_q[row][3];
            float mu  = s * (1.0f / 256.0f);
            float var = q * (1.0f / 256.0f) - mu * mu;
            float rstd = rsqrtf(var + 1e-5f);
            #pragma unroll
            for (int fc = 0; fc < 4; fc++) {
                int col = w * 64 + fc * 16 + l15;
                Y[(size_t)grow * D + col] = (acc[fr][fc][r] - mu) * rstd * gam_c[fc] + bet_c[fc];
            }
        }
    }
}

// ---------------- launch ----------------

extern "C" void kernel_launch(void* const* d_in, const int* in_sizes, int n_in,
                              void* d_out, int out_size, void* d_ws, size_t ws_size,
                              hipStream_t stream) {
    const float* uf    = (const float*)d_in[0];
    const float* itf   = (const float*)d_in[1];
    const int*   ui_e  = (const int*)d_in[2];   // [2, Eui] user->item
    const int*   iu_e  = (const int*)d_in[3];   // [2, Eiu] item->user
    const float* Wu    = (const float*)d_in[4];
    const float* bu    = (const float*)d_in[5];
    const float* Wi    = (const float*)d_in[6];
    const float* bi    = (const float*)d_in[7];
    const float* gamma = (const float*)d_in[8];
    const float* beta  = (const float*)d_in[9];

    int NU  = in_sizes[0] / D;
    int NI  = in_sizes[1] / D;
    int Eui = in_sizes[2] / 2;
    int Eiu = in_sizes[3] / 2;
    int Nmax = NU > NI ? NU : NI;

    float* out   = (float*)d_out;
    float* u_out = out;
    float* i_out = out + (size_t)NU * D;

    // ws layout: Wt_u, Wt_i (bf16 256x256 each), then CSR ints
    __hip_bfloat16* Wt_u = (__hip_bfloat16*)d_ws;
    __hip_bfloat16* Wt_i = Wt_u + 256 * 256;
    int* deg    = (int*)(Wt_i + 256 * 256);
    int* rs     = deg + Nmax;          // Nmax+1
    int* bsums  = rs + Nmax + 1;       // 1024
    int* cursor = bsums + 1024;        // Nmax
    int* csr    = cursor + Nmax;       // Emax

    k_wcvt<<<512, 256, 0, stream>>>(Wu, Wi, Wt_u, Wt_i);

    auto run_side = [&](const float* srcf, const float* tgtf, const int* edges, int E,
                        int N, const __hip_bfloat16* Wt, const float* bias, float* y) {
        const int* esrc = edges;
        const int* edst = edges + E;
        hipMemsetAsync(deg, 0, (size_t)N * sizeof(int), stream);
        hipMemsetAsync(cursor, 0, (size_t)N * sizeof(int), stream);
        k_hist<<<(E + 255) / 256, 256, 0, stream>>>(edst, E, deg);
        int nb = (N + 1023) / 1024;
        k_scan_block<<<nb, 1024, 0, stream>>>(deg, N, rs, bsums);
        k_scan_sums<<<1, 1024, 0, stream>>>(bsums, nb);
        k_finalize_rs<<<(N + 255) / 256, 256, 0, stream>>>(N, rs, bsums);
        k_fill<<<(E + 255) / 256, 256, 0, stream>>>(esrc, edst, E, rs, cursor, csr);
        k_msg_x<<<(N + 3) / 4, 256, 0, stream>>>(srcf, tgtf, rs, csr, N, y);
        k_gemm_mfma_ln<<<(N + BM - 1) / BM, 256, 0, stream>>>(y, Wt, bias, gamma, beta, N, y);
    };

    // users: messages from items via item_user_edge_index
    run_side(itf, uf, iu_e, Eiu, NU, Wt_u, bu, u_out);
    // items: messages from users via user_item_edge_index
    run_side(uf, itf, ui_e, Eui, NI, Wt_i, bi, i_out);
}